// Round 6
// baseline (153.711 us; speedup 1.0000x reference)
//
#include <hip/hip_runtime.h>
#include <hip/hip_bf16.h>
#include <math.h>

// Problem constants (Mask2Former pixel decoder / MS-deformable attention)
#define BB 4
#define SEQ 5376
#define DD 256
#define NH 8
#define NL 3
#define NP 4
#define DH 32
#define MTOT (BB * SEQ)          // 21504 rows for all GEMMs

typedef __attribute__((ext_vector_type(8))) short bf16x8;
typedef __attribute__((ext_vector_type(4))) float f32x4;

__device__ __forceinline__ ushort f2b(float f) {
    __hip_bfloat16 h = __float2bfloat16(f);
    return *reinterpret_cast<ushort*>(&h);
}

__device__ __forceinline__ bf16x8 pack8(float4 a, float4 b) {
    bf16x8 r;
    r[0] = (short)f2b(a.x); r[1] = (short)f2b(a.y);
    r[2] = (short)f2b(a.z); r[3] = (short)f2b(a.w);
    r[4] = (short)f2b(b.x); r[5] = (short)f2b(b.y);
    r[6] = (short)f2b(b.z); r[7] = (short)f2b(b.w);
    return r;
}

// ---------------------------------------------------------------------------
// Transpose all 4 weight matrices (K=256 each) into Wt[800][256] bf16.
// Rows: [0,256)=Wv, [256,448)=Wo, [448,544)=Wa, [544,800)=Wout.
// Block 800: build combined bias for the merged off+logits GEMM (288 floats).
// ---------------------------------------------------------------------------
__global__ __launch_bounds__(256) void prep_w(
    const float* __restrict__ Wv, const float* __restrict__ Wo,
    const float* __restrict__ Wa, const float* __restrict__ Wout,
    const float* __restrict__ bo, const float* __restrict__ ba,
    ushort* __restrict__ Wt, float* __restrict__ bcomb) {
    int row = blockIdx.x;
    int k = threadIdx.x;
    if (row == 800) {
        for (int i = k; i < 288; i += 256)
            bcomb[i] = (i < 192) ? bo[i] : ba[i - 192];
        return;
    }
    const float* src;
    int N, n;
    if (row < 256)      { src = Wv;   N = 256; n = row; }
    else if (row < 448) { src = Wo;   N = 192; n = row - 256; }
    else if (row < 544) { src = Wa;   N = 96;  n = row - 448; }
    else                { src = Wout; N = 256; n = row - 544; }
    float v = src[(size_t)k * N + n];
    Wt[(size_t)row * 256 + k] = f2b(v);
}

// ---------------------------------------------------------------------------
// bf16 MFMA GEMM, A staged from fp32 (optionally A1+A2), converted to bf16
// during LDS write. BM=128, BN=64, BK=32; 4 waves 2x2; 4x2 fragments of
// mfma_f32_16x16x32_bf16. OBF: bf16 output, else fp32. N guarded.
// ---------------------------------------------------------------------------
template<bool ADD, bool OBF>
__global__ __launch_bounds__(256) void gemm_mfma_f32a(
    const float* __restrict__ A1, const float* __restrict__ A2,
    const ushort* __restrict__ Wt,
    const float* __restrict__ bias, void* __restrict__ Cout,
    int M, int N, int K) {
    const int BM = 128, BN = 64, BK = 32, PK = 40;
    __shared__ ushort As[BM][PK];
    __shared__ ushort Bs[BN][PK];
    int bm = blockIdx.y * BM;
    int bn = blockIdx.x * BN;
    int tid = threadIdx.x;
    int lane = tid & 63;
    int wid = tid >> 6;
    int wr = wid >> 1, wc = wid & 1;
    int lr = lane & 15;
    int kg = lane >> 4;

    f32x4 acc[4][2] = {};

    for (int k0 = 0; k0 < K; k0 += BK) {
        // stage A: 128 rows x 32 cols fp32 -> bf16; 512 chunks of 8
        #pragma unroll
        for (int c = 0; c < 2; c++) {
            int e = tid + 256 * c;
            int row = e >> 2, qq = e & 3;
            size_t gi = (size_t)(bm + row) * K + k0 + 8 * qq;
            float4 f0 = *(const float4*)(A1 + gi);
            float4 f1 = *(const float4*)(A1 + gi + 4);
            if (ADD) {
                float4 p0 = *(const float4*)(A2 + gi);
                float4 p1 = *(const float4*)(A2 + gi + 4);
                f0.x += p0.x; f0.y += p0.y; f0.z += p0.z; f0.w += p0.w;
                f1.x += p1.x; f1.y += p1.y; f1.z += p1.z; f1.w += p1.w;
            }
            *(bf16x8*)&As[row][8 * qq] = pack8(f0, f1);
        }
        // stage B: 64 rows x 32 bf16; 256 chunks
        {
            int row = tid >> 2, qq = tid & 3;
            int gn = bn + row;
            bf16x8 v = {0, 0, 0, 0, 0, 0, 0, 0};
            if (gn < N) v = *(const bf16x8*)(Wt + (size_t)gn * K + k0 + 8 * qq);
            *(bf16x8*)&Bs[row][8 * qq] = v;
        }
        __syncthreads();
        bf16x8 af[4], bfr[2];
        #pragma unroll
        for (int mf = 0; mf < 4; mf++)
            af[mf] = *(bf16x8*)&As[wr * 64 + mf * 16 + lr][kg * 8];
        #pragma unroll
        for (int nf = 0; nf < 2; nf++)
            bfr[nf] = *(bf16x8*)&Bs[wc * 32 + nf * 16 + lr][kg * 8];
        #pragma unroll
        for (int mf = 0; mf < 4; mf++)
            #pragma unroll
            for (int nf = 0; nf < 2; nf++)
                acc[mf][nf] = __builtin_amdgcn_mfma_f32_16x16x32_bf16(
                    af[mf], bfr[nf], acc[mf][nf], 0, 0, 0);
        __syncthreads();
    }

    #pragma unroll
    for (int nf = 0; nf < 2; nf++) {
        int gc = bn + wc * 32 + nf * 16 + lr;
        if (gc >= N) continue;
        float bv = bias[gc];
        #pragma unroll
        for (int mf = 0; mf < 4; mf++) {
            int gr0 = bm + wr * 64 + mf * 16 + kg * 4;
            #pragma unroll
            for (int r = 0; r < 4; r++) {
                float v = acc[mf][nf][r] + bv;
                if constexpr (OBF)
                    ((ushort*)Cout)[(size_t)(gr0 + r) * N + gc] = f2b(v);
                else
                    ((float*)Cout)[(size_t)(gr0 + r) * N + gc] = v;
            }
        }
    }
}

// ---------------------------------------------------------------------------
// bf16-A MFMA GEMM (final projection): identical compute, A already bf16.
// ---------------------------------------------------------------------------
template<bool OBF>
__global__ __launch_bounds__(256) void gemm_mfma(
    const ushort* __restrict__ A, const ushort* __restrict__ Wt,
    const float* __restrict__ bias, void* __restrict__ Cout,
    int M, int N, int K) {
    const int BM = 128, BN = 64, BK = 32, PK = 40;
    __shared__ ushort As[BM][PK];
    __shared__ ushort Bs[BN][PK];
    int bm = blockIdx.y * BM;
    int bn = blockIdx.x * BN;
    int tid = threadIdx.x;
    int lane = tid & 63;
    int wid = tid >> 6;
    int wr = wid >> 1, wc = wid & 1;
    int lr = lane & 15;
    int kg = lane >> 4;

    f32x4 acc[4][2] = {};

    for (int k0 = 0; k0 < K; k0 += BK) {
        #pragma unroll
        for (int c = 0; c < 2; c++) {
            int e = tid + 256 * c;
            int row = e >> 2, qq = e & 3;
            const ushort* src = A + (size_t)(bm + row) * K + k0 + 8 * qq;
            *(bf16x8*)&As[row][8 * qq] = *(const bf16x8*)src;
        }
        {
            int row = tid >> 2, qq = tid & 3;
            int gn = bn + row;
            bf16x8 v = {0, 0, 0, 0, 0, 0, 0, 0};
            if (gn < N) v = *(const bf16x8*)(Wt + (size_t)gn * K + k0 + 8 * qq);
            *(bf16x8*)&Bs[row][8 * qq] = v;
        }
        __syncthreads();
        bf16x8 af[4], bfr[2];
        #pragma unroll
        for (int mf = 0; mf < 4; mf++)
            af[mf] = *(bf16x8*)&As[wr * 64 + mf * 16 + lr][kg * 8];
        #pragma unroll
        for (int nf = 0; nf < 2; nf++)
            bfr[nf] = *(bf16x8*)&Bs[wc * 32 + nf * 16 + lr][kg * 8];
        #pragma unroll
        for (int mf = 0; mf < 4; mf++)
            #pragma unroll
            for (int nf = 0; nf < 2; nf++)
                acc[mf][nf] = __builtin_amdgcn_mfma_f32_16x16x32_bf16(
                    af[mf], bfr[nf], acc[mf][nf], 0, 0, 0);
        __syncthreads();
    }

    #pragma unroll
    for (int nf = 0; nf < 2; nf++) {
        int gc = bn + wc * 32 + nf * 16 + lr;
        if (gc >= N) continue;
        float bv = bias[gc];
        #pragma unroll
        for (int mf = 0; mf < 4; mf++) {
            int gr0 = bm + wr * 64 + mf * 16 + kg * 4;
            #pragma unroll
            for (int r = 0; r < 4; r++) {
                float v = acc[mf][nf][r] + bv;
                if constexpr (OBF)
                    ((ushort*)Cout)[(size_t)(gr0 + r) * N + gc] = f2b(v);
                else
                    ((float*)Cout)[(size_t)(gr0 + r) * N + gc] = v;
            }
        }
    }
}

// ---------------------------------------------------------------------------
// Deformable sampling v4: fused softmax + tap table + pipelined 16B gathers.
// Block = 8 queries (4 waves, 2 queries/wave).
// Phase 1: 1024 slots = 8q x 8h x 16 (lp<12 active). Softmax over the 16-lane
//          group via shfl_xor; writes attn_out; computes tap idx/weights->LDS.
// Phase 2: lane = q2*32 + h*4 + d8; 8 channels (16B) per lane; 2-deep
//          software pipeline over the 12 taps.
// ---------------------------------------------------------------------------
struct Acc8 {
    float a0, a1, a2, a3, a4, a5, a6, a7;
};

__device__ __forceinline__ void fma8(Acc8& acc, float wt, uint4 u) {
    acc.a0 = fmaf(wt, __uint_as_float(u.x << 16), acc.a0);
    acc.a1 = fmaf(wt, __uint_as_float(u.x & 0xffff0000u), acc.a1);
    acc.a2 = fmaf(wt, __uint_as_float(u.y << 16), acc.a2);
    acc.a3 = fmaf(wt, __uint_as_float(u.y & 0xffff0000u), acc.a3);
    acc.a4 = fmaf(wt, __uint_as_float(u.z << 16), acc.a4);
    acc.a5 = fmaf(wt, __uint_as_float(u.z & 0xffff0000u), acc.a5);
    acc.a6 = fmaf(wt, __uint_as_float(u.w << 16), acc.a6);
    acc.a7 = fmaf(wt, __uint_as_float(u.w & 0xffff0000u), acc.a7);
}

__global__ __launch_bounds__(256) void msda_sample_v4(
    const ushort* __restrict__ value, const float* __restrict__ comb,
    const float* __restrict__ refp, float* __restrict__ attn_out,
    ushort* __restrict__ out) {
    __shared__ int4   s_idx[8][8][13];
    __shared__ float4 s_w[8][8][13];
    int tid = threadIdx.x;
    int bq0 = blockIdx.x * 8;

    // ---- phase 1: softmax + tap setup ----
    #pragma unroll
    for (int it = 0; it < 4; it++) {
        int t = tid + it * 256;
        int lp = t & 15;
        int qh = t >> 4;                 // 0..63
        int q = qh >> 3, h = qh & 7;
        int bq = bq0 + q;
        bool active = lp < 12;
        const float* crow = comb + (size_t)bq * 288;
        float logit = active ? crow[192 + h * 12 + lp] : -INFINITY;
        float m = logit;
        m = fmaxf(m, __shfl_xor(m, 1, 16));
        m = fmaxf(m, __shfl_xor(m, 2, 16));
        m = fmaxf(m, __shfl_xor(m, 4, 16));
        m = fmaxf(m, __shfl_xor(m, 8, 16));
        float e = active ? expf(logit - m) : 0.f;
        float s = e;
        s += __shfl_xor(s, 1, 16);
        s += __shfl_xor(s, 2, 16);
        s += __shfl_xor(s, 4, 16);
        s += __shfl_xor(s, 8, 16);
        float aw = e / s;
        if (active) {
            attn_out[(size_t)bq * 96 + h * 12 + lp] = aw;
            int l = lp >> 2;
            int b = bq / SEQ;
            int Wl = 64 >> l;
            float fW = (float)Wl;
            float rx = refp[(size_t)bq * 6 + 2 * l];
            float ry = refp[(size_t)bq * 6 + 2 * l + 1];
            float ox = crow[h * 24 + lp * 2];
            float oy = crow[h * 24 + lp * 2 + 1];
            float x = rx * fW + ox - 0.5f;
            float y = ry * fW + oy - 0.5f;
            float x0f = floorf(x), y0f = floorf(y);
            float wx = x - x0f, wy = y - y0f;
            int x0 = (int)x0f, y0 = (int)y0f;
            int x1 = x0 + 1, y1 = y0 + 1;
            float vx0 = (x0 >= 0 && x0 < Wl) ? 1.f : 0.f;
            float vx1 = (x1 >= 0 && x1 < Wl) ? 1.f : 0.f;
            float vy0 = (y0 >= 0 && y0 < Wl) ? 1.f : 0.f;   // square levels
            float vy1 = (y1 >= 0 && y1 < Wl) ? 1.f : 0.f;
            int xc0 = min(max(x0, 0), Wl - 1);
            int xc1 = min(max(x1, 0), Wl - 1);
            int yc0 = min(max(y0, 0), Wl - 1);
            int yc1 = min(max(y1, 0), Wl - 1);
            int st = (l == 0) ? 0 : ((l == 1) ? 4096 : 5120);
            int rowbase = b * SEQ + st;
            s_idx[q][h][lp] = make_int4((rowbase + yc0 * Wl + xc0) << 8,
                                        (rowbase + yc0 * Wl + xc1) << 8,
                                        (rowbase + yc1 * Wl + xc0) << 8,
                                        (rowbase + yc1 * Wl + xc1) << 8);
            s_w[q][h][lp] = make_float4(aw * (1.f - wx) * (1.f - wy) * vx0 * vy0,
                                        aw * wx * (1.f - wy) * vx1 * vy0,
                                        aw * (1.f - wx) * wy * vx0 * vy1,
                                        aw * wx * wy * vx1 * vy1);
        }
    }
    __syncthreads();

    // ---- phase 2: pipelined gather + FMA ----
    int wave = tid >> 6, lane = tid & 63;
    int q2 = lane >> 5;
    int h = (lane >> 2) & 7;
    int d8 = lane & 3;
    int q = wave * 2 + q2;
    int bq = bq0 + q;
    int ch0 = h * 32 + d8 * 8;
    const ushort* vb = value + ch0;

    Acc8 acc = {0.f, 0.f, 0.f, 0.f, 0.f, 0.f, 0.f, 0.f};

    int4 iA = s_idx[q][h][0];
    float4 wA = s_w[q][h][0];
    uint4 a0 = *(const uint4*)(vb + iA.x);
    uint4 a1 = *(const uint4*)(vb + iA.y);
    uint4 a2 = *(const uint4*)(vb + iA.z);
    uint4 a3 = *(const uint4*)(vb + iA.w);

    #pragma unroll
    for (int lp = 0; lp < 12; lp++) {
        int4 iB;
        float4 wB;
        uint4 b0, b1, b2, b3;
        if (lp < 11) {
            iB = s_idx[q][h][lp + 1];
            wB = s_w[q][h][lp + 1];
            b0 = *(const uint4*)(vb + iB.x);
            b1 = *(const uint4*)(vb + iB.y);
            b2 = *(const uint4*)(vb + iB.z);
            b3 = *(const uint4*)(vb + iB.w);
        }
        fma8(acc, wA.x, a0);
        fma8(acc, wA.y, a1);
        fma8(acc, wA.z, a2);
        fma8(acc, wA.w, a3);
        if (lp < 11) {
            iA = iB; wA = wB;
            a0 = b0; a1 = b1; a2 = b2; a3 = b3;
        }
    }

    bf16x8 o;
    o[0] = (short)f2b(acc.a0); o[1] = (short)f2b(acc.a1);
    o[2] = (short)f2b(acc.a2); o[3] = (short)f2b(acc.a3);
    o[4] = (short)f2b(acc.a4); o[5] = (short)f2b(acc.a5);
    o[6] = (short)f2b(acc.a6); o[7] = (short)f2b(acc.a7);
    *(bf16x8*)(out + (size_t)bq * 256 + ch0) = o;
}

// ---------------------------------------------------------------------------
extern "C" void kernel_launch(void* const* d_in, const int* in_sizes, int n_in,
                              void* d_out, int out_size, void* d_ws, size_t ws_size,
                              hipStream_t stream) {
    const float* hidden = (const float*)d_in[0];
    const float* pos    = (const float*)d_in[1];
    const float* refp   = (const float*)d_in[2];
    const float* Wv     = (const float*)d_in[3];
    const float* bv     = (const float*)d_in[4];
    const float* Wo     = (const float*)d_in[5];
    const float* bo     = (const float*)d_in[6];
    const float* Wa     = (const float*)d_in[7];
    const float* ba     = (const float*)d_in[8];
    const float* Wout   = (const float*)d_in[9];
    const float* bout   = (const float*)d_in[10];

    float* out      = (float*)d_out;                       // (B,SEQ,256)
    float* attn_out = out + (size_t)BB * SEQ * DD;         // (B,SEQ,NH,NL,NP)

    const size_t BSD = (size_t)BB * SEQ * DD;              // 5,505,024
    char* w = (char*)d_ws;
    ushort* value_bf = (ushort*)w;  w += BSD * 2;                 // bf16 value
    float*  comb     = (float*)w;   w += (size_t)MTOT * 288 * 4;  // off|logits
    ushort* sampb    = (ushort*)w;  w += BSD * 2;                 // bf16 sampled
    ushort* Wt       = (ushort*)w;  w += (size_t)800 * 256 * 2;   // bf16 weights^T
    float*  bcomb    = (float*)w;                                 // 288 bias

    // 1. prep: transpose weights to bf16 [N][K] + combined bias
    prep_w<<<801, 256, 0, stream>>>(Wv, Wo, Wa, Wout, bo, ba, Wt, bcomb);

    const ushort* Wv_t    = Wt;
    const ushort* Wcomb_t = Wt + (size_t)256 * 256;   // rows: 192 Wo + 96 Wa
    const ushort* Wout_t  = Wt + (size_t)544 * 256;

    // 2. value = bf16(hidden) @ Wv + bv  -> bf16  (A converted in staging)
    {
        dim3 grid(DD / 64, MTOT / 128);
        gemm_mfma_f32a<false, true><<<grid, 256, 0, stream>>>(
            hidden, nullptr, Wv_t, bv, value_bf, MTOT, DD, DD);
    }
    // 3. comb = bf16(hidden+pos) @ [Wo|Wa] + [bo|ba]  (N=288, fp32 out)
    {
        dim3 grid(5, MTOT / 128);
        gemm_mfma_f32a<true, false><<<grid, 256, 0, stream>>>(
            hidden, pos, Wcomb_t, bcomb, comb, MTOT, 288, DD);
    }
    // 4. fused softmax + deformable sampling -> attn_out + sampled bf16
    {
        msda_sample_v4<<<MTOT / 8, 256, 0, stream>>>(value_bf, comb, refp,
                                                     attn_out, sampb);
    }
    // 5. out = sampled @ Wout + bout -> d_out
    {
        dim3 grid(DD / 64, MTOT / 128);
        gemm_mfma<false><<<grid, 256, 0, stream>>>(sampb, Wout_t, bout, out, MTOT, DD, DD);
    }
}

// Round 7
// 103.508 us; speedup vs baseline: 1.4850x; 1.4850x over previous
//
#include <hip/hip_runtime.h>
#include <hip/hip_bf16.h>
#include <math.h>

// Problem constants (Mask2Former pixel decoder / MS-deformable attention)
#define BB 4
#define SEQ 5376
#define DD 256
#define NH 8
#define NL 3
#define NP 4
#define DH 32
#define MTOT (BB * SEQ)          // 21504 rows for all GEMMs

typedef __attribute__((ext_vector_type(8))) short bf16x8;
typedef __attribute__((ext_vector_type(4))) float f32x4;

__device__ __forceinline__ ushort f2b(float f) {
    __hip_bfloat16 h = __float2bfloat16(f);
    return *reinterpret_cast<ushort*>(&h);
}

// ---------------------------------------------------------------------------
// Convert hidden -> bf16 and (hidden+pos) -> bf16 in one pass.
// ---------------------------------------------------------------------------
__global__ void prep_acts(const float4* __restrict__ h, const float4* __restrict__ p,
                          ushort4* __restrict__ hb, ushort4* __restrict__ hsb, int n4) {
    int i = blockIdx.x * blockDim.x + threadIdx.x;
    int stride = gridDim.x * blockDim.x;
    for (; i < n4; i += stride) {
        float4 a = h[i], b = p[i];
        ushort4 ua, us;
        ua.x = f2b(a.x); ua.y = f2b(a.y); ua.z = f2b(a.z); ua.w = f2b(a.w);
        us.x = f2b(a.x + b.x); us.y = f2b(a.y + b.y);
        us.z = f2b(a.z + b.z); us.w = f2b(a.w + b.w);
        hb[i] = ua;
        hsb[i] = us;
    }
}

// ---------------------------------------------------------------------------
// Transpose all 4 weight matrices (K=256 each) into Wt[800][256] bf16.
// Rows: [0,256)=Wv, [256,448)=Wo, [448,544)=Wa, [544,800)=Wout.
// Block 800: build combined bias for the merged off+logits GEMM (288 floats).
// ---------------------------------------------------------------------------
__global__ __launch_bounds__(256) void prep_w(
    const float* __restrict__ Wv, const float* __restrict__ Wo,
    const float* __restrict__ Wa, const float* __restrict__ Wout,
    const float* __restrict__ bo, const float* __restrict__ ba,
    ushort* __restrict__ Wt, float* __restrict__ bcomb) {
    int row = blockIdx.x;
    int k = threadIdx.x;
    if (row == 800) {
        for (int i = k; i < 288; i += 256)
            bcomb[i] = (i < 192) ? bo[i] : ba[i - 192];
        return;
    }
    const float* src;
    int N, n;
    if (row < 256)      { src = Wv;   N = 256; n = row; }
    else if (row < 448) { src = Wo;   N = 192; n = row - 256; }
    else if (row < 544) { src = Wa;   N = 96;  n = row - 448; }
    else                { src = Wout; N = 256; n = row - 544; }
    float v = src[(size_t)k * N + n];
    Wt[(size_t)row * 256 + k] = f2b(v);
}

// ---------------------------------------------------------------------------
// bf16 MFMA GEMM: C[M,N] = A[M,K]@W[K,N] + bias  (A bf16 [M][K], Wt bf16 [N][K])
// BM=128, BN=64, BK=32. 256 threads = 4 waves 2x2; wave tile 64x32 via 4x2
// fragments of mfma_f32_16x16x32_bf16. OBF: bf16 output, else fp32. N guarded.
// ---------------------------------------------------------------------------
template<bool OBF>
__global__ __launch_bounds__(256) void gemm_mfma(
    const ushort* __restrict__ A, const ushort* __restrict__ Wt,
    const float* __restrict__ bias, void* __restrict__ Cout,
    int M, int N, int K) {
    const int BM = 128, BN = 64, BK = 32, PK = 40;   // PK: padded LDS row (elems)
    __shared__ ushort As[BM][PK];
    __shared__ ushort Bs[BN][PK];
    int bm = blockIdx.y * BM;
    int bn = blockIdx.x * BN;
    int tid = threadIdx.x;
    int lane = tid & 63;
    int wid = tid >> 6;
    int wr = wid >> 1, wc = wid & 1;     // 2x2 wave grid
    int lr = lane & 15;                  // row-in-frag (A) / col (B,C)
    int kg = lane >> 4;                  // k-group 0..3

    f32x4 acc[4][2] = {};

    for (int k0 = 0; k0 < K; k0 += BK) {
        // stage A: 128 rows x 32 bf16; 512 chunks of 8 bf16 (16B)
        #pragma unroll
        for (int c = 0; c < 2; c++) {
            int e = tid + 256 * c;
            int row = e >> 2, q = e & 3;
            const ushort* src = A + (size_t)(bm + row) * K + k0 + 8 * q;
            *(bf16x8*)&As[row][8 * q] = *(const bf16x8*)src;
        }
        // stage B: 64 rows x 32 bf16; 256 chunks
        {
            int row = tid >> 2, q = tid & 3;
            int gn = bn + row;
            bf16x8 v = {0, 0, 0, 0, 0, 0, 0, 0};
            if (gn < N) v = *(const bf16x8*)(Wt + (size_t)gn * K + k0 + 8 * q);
            *(bf16x8*)&Bs[row][8 * q] = v;
        }
        __syncthreads();
        bf16x8 af[4], bfr[2];
        #pragma unroll
        for (int mf = 0; mf < 4; mf++)
            af[mf] = *(bf16x8*)&As[wr * 64 + mf * 16 + lr][kg * 8];
        #pragma unroll
        for (int nf = 0; nf < 2; nf++)
            bfr[nf] = *(bf16x8*)&Bs[wc * 32 + nf * 16 + lr][kg * 8];
        #pragma unroll
        for (int mf = 0; mf < 4; mf++)
            #pragma unroll
            for (int nf = 0; nf < 2; nf++)
                acc[mf][nf] = __builtin_amdgcn_mfma_f32_16x16x32_bf16(
                    af[mf], bfr[nf], acc[mf][nf], 0, 0, 0);
        __syncthreads();
    }

    // epilogue: C[row][col] = acc + bias[col]
    #pragma unroll
    for (int nf = 0; nf < 2; nf++) {
        int gc = bn + wc * 32 + nf * 16 + lr;
        if (gc >= N) continue;
        float bv = bias[gc];
        #pragma unroll
        for (int mf = 0; mf < 4; mf++) {
            int gr0 = bm + wr * 64 + mf * 16 + kg * 4;
            #pragma unroll
            for (int r = 0; r < 4; r++) {
                float v = acc[mf][nf][r] + bv;
                if constexpr (OBF)
                    ((ushort*)Cout)[(size_t)(gr0 + r) * N + gc] = f2b(v);
                else
                    ((float*)Cout)[(size_t)(gr0 + r) * N + gc] = v;
            }
        }
    }
}

// ---------------------------------------------------------------------------
// Deformable sampling v5: v3 gather structure + fused softmax + XCD swizzle.
// Block = 4 queries (4 waves). Phase 1: 512 slots = 4q x 8h x 16 (lp<12
// active); 16-lane shfl softmax; writes attn_out; tap idx/weights -> LDS.
// Phase 2: wave q, lane = h*8+d4; per tap 4x 8B bf16 gathers + 16 fma.
// XCD-chunked swizzle: each XCD gets a contiguous 672-block span so the tap
// window (~1 MB of value) fits its private L2.
// ---------------------------------------------------------------------------
__global__ __launch_bounds__(256) void msda_sample_v5(
    const ushort* __restrict__ value, const float* __restrict__ comb,
    const float* __restrict__ refp, float* __restrict__ attn_out,
    ushort* __restrict__ out) {
    __shared__ int4   s_idx[4][8][13];   // [q][h][lp], pad 12->13
    __shared__ float4 s_w[4][8][13];
    int tid = threadIdx.x;
    // XCD-chunked swizzle (gridDim.x = 5376, divisible by 8)
    int bid = blockIdx.x;
    int swz = (bid & 7) * (MTOT / 4 / 8) + (bid >> 3);
    int bq0 = swz * 4;

    // ---- phase 1: softmax + tap setup (2 x 256 = 512 slots) ----
    #pragma unroll
    for (int it = 0; it < 2; it++) {
        int t = tid + it * 256;
        int lp = t & 15;
        int qh = t >> 4;                 // 0..31
        int q = qh >> 3, h = qh & 7;
        int bq = bq0 + q;
        bool active = lp < 12;
        const float* crow = comb + (size_t)bq * 288;
        float logit = active ? crow[192 + h * 12 + lp] : -INFINITY;
        float m = logit;
        m = fmaxf(m, __shfl_xor(m, 1, 16));
        m = fmaxf(m, __shfl_xor(m, 2, 16));
        m = fmaxf(m, __shfl_xor(m, 4, 16));
        m = fmaxf(m, __shfl_xor(m, 8, 16));
        float e = active ? expf(logit - m) : 0.f;
        float s = e;
        s += __shfl_xor(s, 1, 16);
        s += __shfl_xor(s, 2, 16);
        s += __shfl_xor(s, 4, 16);
        s += __shfl_xor(s, 8, 16);
        float aw = e / s;
        if (active) {
            attn_out[(size_t)bq * 96 + h * 12 + lp] = aw;
            int l = lp >> 2;
            int b = bq / SEQ;
            int Wl = 64 >> l;
            float fW = (float)Wl;
            float rx = refp[(size_t)bq * 6 + 2 * l];
            float ry = refp[(size_t)bq * 6 + 2 * l + 1];
            float ox = crow[h * 24 + lp * 2];
            float oy = crow[h * 24 + lp * 2 + 1];
            float x = rx * fW + ox - 0.5f;
            float y = ry * fW + oy - 0.5f;
            float x0f = floorf(x), y0f = floorf(y);
            float wx = x - x0f, wy = y - y0f;
            int x0 = (int)x0f, y0 = (int)y0f;
            int x1 = x0 + 1, y1 = y0 + 1;
            float vx0 = (x0 >= 0 && x0 < Wl) ? 1.f : 0.f;
            float vx1 = (x1 >= 0 && x1 < Wl) ? 1.f : 0.f;
            float vy0 = (y0 >= 0 && y0 < Wl) ? 1.f : 0.f;   // square levels
            float vy1 = (y1 >= 0 && y1 < Wl) ? 1.f : 0.f;
            int xc0 = min(max(x0, 0), Wl - 1);
            int xc1 = min(max(x1, 0), Wl - 1);
            int yc0 = min(max(y0, 0), Wl - 1);
            int yc1 = min(max(y1, 0), Wl - 1);
            int st = (l == 0) ? 0 : ((l == 1) ? 4096 : 5120);
            int rowbase = b * SEQ + st;
            s_idx[q][h][lp] = make_int4((rowbase + yc0 * Wl + xc0) << 8,
                                        (rowbase + yc0 * Wl + xc1) << 8,
                                        (rowbase + yc1 * Wl + xc0) << 8,
                                        (rowbase + yc1 * Wl + xc1) << 8);
            s_w[q][h][lp] = make_float4(aw * (1.f - wx) * (1.f - wy) * vx0 * vy0,
                                        aw * wx * (1.f - wy) * vx1 * vy0,
                                        aw * (1.f - wx) * wy * vx0 * vy1,
                                        aw * wx * wy * vx1 * vy1);
        }
    }
    __syncthreads();

    // ---- phase 2: gather + FMA (wave = query; lane = h*8 + d4) ----
    int wave = tid >> 6, lane = tid & 63;
    int h = lane >> 3, d4 = lane & 7;
    int bq = bq0 + wave;
    int ch0 = h * 32 + d4 * 4;
    const ushort* vb = value + ch0;
    float4 acc = make_float4(0.f, 0.f, 0.f, 0.f);
    #pragma unroll
    for (int lp = 0; lp < 12; lp++) {
        int4 ii = s_idx[wave][h][lp];
        float4 ww = s_w[wave][h][lp];
        uint2 u0 = *(const uint2*)(vb + ii.x);
        uint2 u1 = *(const uint2*)(vb + ii.y);
        uint2 u2 = *(const uint2*)(vb + ii.z);
        uint2 u3 = *(const uint2*)(vb + ii.w);
        acc.x = fmaf(ww.x, __uint_as_float(u0.x << 16), acc.x);
        acc.y = fmaf(ww.x, __uint_as_float(u0.x & 0xffff0000u), acc.y);
        acc.z = fmaf(ww.x, __uint_as_float(u0.y << 16), acc.z);
        acc.w = fmaf(ww.x, __uint_as_float(u0.y & 0xffff0000u), acc.w);
        acc.x = fmaf(ww.y, __uint_as_float(u1.x << 16), acc.x);
        acc.y = fmaf(ww.y, __uint_as_float(u1.x & 0xffff0000u), acc.y);
        acc.z = fmaf(ww.y, __uint_as_float(u1.y << 16), acc.z);
        acc.w = fmaf(ww.y, __uint_as_float(u1.y & 0xffff0000u), acc.w);
        acc.x = fmaf(ww.z, __uint_as_float(u2.x << 16), acc.x);
        acc.y = fmaf(ww.z, __uint_as_float(u2.x & 0xffff0000u), acc.y);
        acc.z = fmaf(ww.z, __uint_as_float(u2.y << 16), acc.z);
        acc.w = fmaf(ww.z, __uint_as_float(u2.y & 0xffff0000u), acc.w);
        acc.x = fmaf(ww.w, __uint_as_float(u3.x << 16), acc.x);
        acc.y = fmaf(ww.w, __uint_as_float(u3.x & 0xffff0000u), acc.y);
        acc.z = fmaf(ww.w, __uint_as_float(u3.y << 16), acc.z);
        acc.w = fmaf(ww.w, __uint_as_float(u3.y & 0xffff0000u), acc.w);
    }
    ushort4 o;
    o.x = f2b(acc.x); o.y = f2b(acc.y); o.z = f2b(acc.z); o.w = f2b(acc.w);
    *(ushort4*)(out + (size_t)bq * 256 + ch0) = o;
}

// ---------------------------------------------------------------------------
extern "C" void kernel_launch(void* const* d_in, const int* in_sizes, int n_in,
                              void* d_out, int out_size, void* d_ws, size_t ws_size,
                              hipStream_t stream) {
    const float* hidden = (const float*)d_in[0];
    const float* pos    = (const float*)d_in[1];
    const float* refp   = (const float*)d_in[2];
    const float* Wv     = (const float*)d_in[3];
    const float* bv     = (const float*)d_in[4];
    const float* Wo     = (const float*)d_in[5];
    const float* bo     = (const float*)d_in[6];
    const float* Wa     = (const float*)d_in[7];
    const float* ba     = (const float*)d_in[8];
    const float* Wout   = (const float*)d_in[9];
    const float* bout   = (const float*)d_in[10];

    float* out      = (float*)d_out;                       // (B,SEQ,256)
    float* attn_out = out + (size_t)BB * SEQ * DD;         // (B,SEQ,NH,NL,NP)

    const size_t BSD = (size_t)BB * SEQ * DD;              // 5,505,024
    char* w = (char*)d_ws;
    ushort* value_bf = (ushort*)w;  w += BSD * 2;                 // bf16 value
    float*  comb     = (float*)w;   w += (size_t)MTOT * 288 * 4;  // off|logits
    ushort* sampb    = (ushort*)w;  w += BSD * 2;                 // bf16 sampled
    ushort* hb       = (ushort*)w;  w += BSD * 2;                 // bf16 hidden
    ushort* hsb      = (ushort*)w;  w += BSD * 2;                 // bf16 hidden+pos
    ushort* Wt       = (ushort*)w;  w += (size_t)800 * 256 * 2;   // bf16 weights^T
    float*  bcomb    = (float*)w;                                 // 288 bias

    // 1. prep: hidden->bf16, hidden+pos->bf16
    {
        int n4 = (int)(BSD / 4);
        prep_acts<<<2048, 256, 0, stream>>>((const float4*)hidden, (const float4*)pos,
                                            (ushort4*)hb, (ushort4*)hsb, n4);
    }
    // 2. prep: transpose weights to bf16 [N][K] + combined bias
    prep_w<<<801, 256, 0, stream>>>(Wv, Wo, Wa, Wout, bo, ba, Wt, bcomb);

    const ushort* Wv_t    = Wt;
    const ushort* Wcomb_t = Wt + (size_t)256 * 256;   // rows: 192 Wo + 96 Wa
    const ushort* Wout_t  = Wt + (size_t)544 * 256;

    // 3. value = hidden @ Wv + bv  -> bf16
    {
        dim3 grid(DD / 64, MTOT / 128);
        gemm_mfma<true><<<grid, 256, 0, stream>>>(hb, Wv_t, bv, value_bf, MTOT, DD, DD);
    }
    // 4. comb = hs @ [Wo|Wa] + [bo|ba]  (N=288, fp32 out)
    {
        dim3 grid(5, MTOT / 128);
        gemm_mfma<false><<<grid, 256, 0, stream>>>(hsb, Wcomb_t, bcomb, comb, MTOT, 288, DD);
    }
    // 5. fused softmax + deformable sampling -> attn_out + sampled bf16
    {
        msda_sample_v5<<<MTOT / 4, 256, 0, stream>>>(value_bf, comb, refp,
                                                     attn_out, sampb);
    }
    // 6. out = sampled @ Wout + bout -> d_out
    {
        dim3 grid(DD / 64, MTOT / 128);
        gemm_mfma<false><<<grid, 256, 0, stream>>>(sampb, Wout_t, bout, out, MTOT, DD, DD);
    }
}

// Round 8
// 101.777 us; speedup vs baseline: 1.5103x; 1.0170x over previous
//
#include <hip/hip_runtime.h>
#include <hip/hip_bf16.h>
#include <math.h>

// Problem constants (Mask2Former pixel decoder / MS-deformable attention)
#define BB 4
#define SEQ 5376
#define DD 256
#define NH 8
#define NL 3
#define NP 4
#define DH 32
#define MTOT (BB * SEQ)          // 21504 rows for all GEMMs

typedef __attribute__((ext_vector_type(8))) short bf16x8;
typedef __attribute__((ext_vector_type(4))) float f32x4;

__device__ __forceinline__ ushort f2b(float f) {
    __hip_bfloat16 h = __float2bfloat16(f);
    return *reinterpret_cast<ushort*>(&h);
}

// ---------------------------------------------------------------------------
// Convert hidden -> bf16 and (hidden+pos) -> bf16 in one pass.
// ---------------------------------------------------------------------------
__global__ void prep_acts(const float4* __restrict__ h, const float4* __restrict__ p,
                          ushort4* __restrict__ hb, ushort4* __restrict__ hsb, int n4) {
    int i = blockIdx.x * blockDim.x + threadIdx.x;
    int stride = gridDim.x * blockDim.x;
    for (; i < n4; i += stride) {
        float4 a = h[i], b = p[i];
        ushort4 ua, us;
        ua.x = f2b(a.x); ua.y = f2b(a.y); ua.z = f2b(a.z); ua.w = f2b(a.w);
        us.x = f2b(a.x + b.x); us.y = f2b(a.y + b.y);
        us.z = f2b(a.z + b.z); us.w = f2b(a.w + b.w);
        hb[i] = ua;
        hsb[i] = us;
    }
}

// ---------------------------------------------------------------------------
// Transpose all 4 weight matrices (K=256 each) into Wt[800][256] bf16.
// Rows: [0,256)=Wv, [256,448)=Wo, [448,544)=Wa, [544,800)=Wout.
// Block 800: build combined bias for the merged off+logits GEMM (288 floats).
// ---------------------------------------------------------------------------
__global__ __launch_bounds__(256) void prep_w(
    const float* __restrict__ Wv, const float* __restrict__ Wo,
    const float* __restrict__ Wa, const float* __restrict__ Wout,
    const float* __restrict__ bo, const float* __restrict__ ba,
    ushort* __restrict__ Wt, float* __restrict__ bcomb) {
    int row = blockIdx.x;
    int k = threadIdx.x;
    if (row == 800) {
        for (int i = k; i < 288; i += 256)
            bcomb[i] = (i < 192) ? bo[i] : ba[i - 192];
        return;
    }
    const float* src;
    int N, n;
    if (row < 256)      { src = Wv;   N = 256; n = row; }
    else if (row < 448) { src = Wo;   N = 192; n = row - 256; }
    else if (row < 544) { src = Wa;   N = 96;  n = row - 448; }
    else                { src = Wout; N = 256; n = row - 544; }
    float v = src[(size_t)k * N + n];
    Wt[(size_t)row * 256 + k] = f2b(v);
}

// ---------------------------------------------------------------------------
// bf16 MFMA GEMM: C[M,N] = A[M,K]@W[K,N] + bias  (A bf16 [M][K], Wt bf16 [N][K])
// BM=128, BN=64, BK=64. 256 threads = 4 waves 2x2; wave tile 64x32; per
// K-step 2 sub-steps of mfma_f32_16x16x32_bf16 -> 16 MFMA per barrier pair.
// OBF: bf16 output, else fp32. N guarded.
// ---------------------------------------------------------------------------
template<bool OBF>
__global__ __launch_bounds__(256) void gemm_mfma(
    const ushort* __restrict__ A, const ushort* __restrict__ Wt,
    const float* __restrict__ bias, void* __restrict__ Cout,
    int M, int N, int K) {
    const int BM = 128, BN = 64, BK = 64, PK = 72;   // PK: padded LDS row (elems)
    __shared__ ushort As[BM][PK];
    __shared__ ushort Bs[BN][PK];
    int bm = blockIdx.y * BM;
    int bn = blockIdx.x * BN;
    int tid = threadIdx.x;
    int lane = tid & 63;
    int wid = tid >> 6;
    int wr = wid >> 1, wc = wid & 1;     // 2x2 wave grid
    int lr = lane & 15;                  // row-in-frag (A) / col (B,C)
    int kg = lane >> 4;                  // k-group 0..3

    f32x4 acc[4][2] = {};

    for (int k0 = 0; k0 < K; k0 += BK) {
        // stage A: 128 rows x 64 bf16 = 1024 chunks of 8 bf16 (16B)
        #pragma unroll
        for (int c = 0; c < 4; c++) {
            int e = tid + 256 * c;
            int row = e >> 3, q = e & 7;
            const ushort* src = A + (size_t)(bm + row) * K + k0 + 8 * q;
            *(bf16x8*)&As[row][8 * q] = *(const bf16x8*)src;
        }
        // stage B: 64 rows x 64 bf16 = 512 chunks
        #pragma unroll
        for (int c = 0; c < 2; c++) {
            int e = tid + 256 * c;
            int row = e >> 3, q = e & 7;
            int gn = bn + row;
            bf16x8 v = {0, 0, 0, 0, 0, 0, 0, 0};
            if (gn < N) v = *(const bf16x8*)(Wt + (size_t)gn * K + k0 + 8 * q);
            *(bf16x8*)&Bs[row][8 * q] = v;
        }
        __syncthreads();
        #pragma unroll
        for (int ks = 0; ks < 2; ks++) {
            bf16x8 af[4], bfr[2];
            #pragma unroll
            for (int mf = 0; mf < 4; mf++)
                af[mf] = *(bf16x8*)&As[wr * 64 + mf * 16 + lr][ks * 32 + kg * 8];
            #pragma unroll
            for (int nf = 0; nf < 2; nf++)
                bfr[nf] = *(bf16x8*)&Bs[wc * 32 + nf * 16 + lr][ks * 32 + kg * 8];
            #pragma unroll
            for (int mf = 0; mf < 4; mf++)
                #pragma unroll
                for (int nf = 0; nf < 2; nf++)
                    acc[mf][nf] = __builtin_amdgcn_mfma_f32_16x16x32_bf16(
                        af[mf], bfr[nf], acc[mf][nf], 0, 0, 0);
        }
        __syncthreads();
    }

    // epilogue: C[row][col] = acc + bias[col]
    #pragma unroll
    for (int nf = 0; nf < 2; nf++) {
        int gc = bn + wc * 32 + nf * 16 + lr;
        if (gc >= N) continue;
        float bv = bias[gc];
        #pragma unroll
        for (int mf = 0; mf < 4; mf++) {
            int gr0 = bm + wr * 64 + mf * 16 + kg * 4;
            #pragma unroll
            for (int r = 0; r < 4; r++) {
                float v = acc[mf][nf][r] + bv;
                if constexpr (OBF)
                    ((ushort*)Cout)[(size_t)(gr0 + r) * N + gc] = f2b(v);
                else
                    ((float*)Cout)[(size_t)(gr0 + r) * N + gc] = v;
            }
        }
    }
}

// ---------------------------------------------------------------------------
// Deformable sampling v6: fused softmax + tap table; 2 waves per query
// (6 taps each) for doubled TLP, LDS reduction combines the halves.
// Block = 2 queries (4 waves). Phase 1: 256 slots = 2q x 8h x 16 lanes
// (lp<12 active); 16-lane shfl softmax -> attn_out + tap idx/weights in LDS.
// Phase 2: wave = (q, half); lane = h*8+d4 (4 channels); 6 taps; partials
// combined via LDS.
// ---------------------------------------------------------------------------
__global__ __launch_bounds__(256) void msda_sample_v6(
    const ushort* __restrict__ value, const float* __restrict__ comb,
    const float* __restrict__ refp, float* __restrict__ attn_out,
    ushort* __restrict__ out) {
    __shared__ int4   s_idx[2][8][13];   // [q][h][lp], pad 12->13
    __shared__ float4 s_w[2][8][13];
    __shared__ float4 s_red[2][64];
    int tid = threadIdx.x;
    int bq0 = blockIdx.x * 2;

    // ---- phase 1: softmax + tap setup (256 slots, 1 pass) ----
    {
        int lp = tid & 15;
        int qh = tid >> 4;               // 0..15
        int q = qh >> 3, h = qh & 7;
        int bq = bq0 + q;
        bool active = lp < 12;
        const float* crow = comb + (size_t)bq * 288;
        float logit = active ? crow[192 + h * 12 + lp] : -INFINITY;
        float m = logit;
        m = fmaxf(m, __shfl_xor(m, 1, 16));
        m = fmaxf(m, __shfl_xor(m, 2, 16));
        m = fmaxf(m, __shfl_xor(m, 4, 16));
        m = fmaxf(m, __shfl_xor(m, 8, 16));
        float e = active ? expf(logit - m) : 0.f;
        float s = e;
        s += __shfl_xor(s, 1, 16);
        s += __shfl_xor(s, 2, 16);
        s += __shfl_xor(s, 4, 16);
        s += __shfl_xor(s, 8, 16);
        float aw = e / s;
        if (active) {
            attn_out[(size_t)bq * 96 + h * 12 + lp] = aw;
            int l = lp >> 2;
            int b = bq / SEQ;
            int Wl = 64 >> l;
            float fW = (float)Wl;
            float rx = refp[(size_t)bq * 6 + 2 * l];
            float ry = refp[(size_t)bq * 6 + 2 * l + 1];
            float ox = crow[h * 24 + lp * 2];
            float oy = crow[h * 24 + lp * 2 + 1];
            float x = rx * fW + ox - 0.5f;
            float y = ry * fW + oy - 0.5f;
            float x0f = floorf(x), y0f = floorf(y);
            float wx = x - x0f, wy = y - y0f;
            int x0 = (int)x0f, y0 = (int)y0f;
            int x1 = x0 + 1, y1 = y0 + 1;
            float vx0 = (x0 >= 0 && x0 < Wl) ? 1.f : 0.f;
            float vx1 = (x1 >= 0 && x1 < Wl) ? 1.f : 0.f;
            float vy0 = (y0 >= 0 && y0 < Wl) ? 1.f : 0.f;   // square levels
            float vy1 = (y1 >= 0 && y1 < Wl) ? 1.f : 0.f;
            int xc0 = min(max(x0, 0), Wl - 1);
            int xc1 = min(max(x1, 0), Wl - 1);
            int yc0 = min(max(y0, 0), Wl - 1);
            int yc1 = min(max(y1, 0), Wl - 1);
            int st = (l == 0) ? 0 : ((l == 1) ? 4096 : 5120);
            int rowbase = b * SEQ + st;
            s_idx[q][h][lp] = make_int4((rowbase + yc0 * Wl + xc0) << 8,
                                        (rowbase + yc0 * Wl + xc1) << 8,
                                        (rowbase + yc1 * Wl + xc0) << 8,
                                        (rowbase + yc1 * Wl + xc1) << 8);
            s_w[q][h][lp] = make_float4(aw * (1.f - wx) * (1.f - wy) * vx0 * vy0,
                                        aw * wx * (1.f - wy) * vx1 * vy0,
                                        aw * (1.f - wx) * wy * vx0 * vy1,
                                        aw * wx * wy * vx1 * vy1);
        }
    }
    __syncthreads();

    // ---- phase 2: gather + FMA (wave = (q, half); lane = h*8 + d4) ----
    int wave = tid >> 6, lane = tid & 63;
    int q = wave >> 1, half = wave & 1;
    int h = lane >> 3, d4 = lane & 7;
    int bq = bq0 + q;
    int ch0 = h * 32 + d4 * 4;
    const ushort* vb = value + ch0;
    float4 acc = make_float4(0.f, 0.f, 0.f, 0.f);
    #pragma unroll
    for (int j = 0; j < 6; j++) {
        int lp = half * 6 + j;
        int4 ii = s_idx[q][h][lp];
        float4 ww = s_w[q][h][lp];
        uint2 u0 = *(const uint2*)(vb + ii.x);
        uint2 u1 = *(const uint2*)(vb + ii.y);
        uint2 u2 = *(const uint2*)(vb + ii.z);
        uint2 u3 = *(const uint2*)(vb + ii.w);
        acc.x = fmaf(ww.x, __uint_as_float(u0.x << 16), acc.x);
        acc.y = fmaf(ww.x, __uint_as_float(u0.x & 0xffff0000u), acc.y);
        acc.z = fmaf(ww.x, __uint_as_float(u0.y << 16), acc.z);
        acc.w = fmaf(ww.x, __uint_as_float(u0.y & 0xffff0000u), acc.w);
        acc.x = fmaf(ww.y, __uint_as_float(u1.x << 16), acc.x);
        acc.y = fmaf(ww.y, __uint_as_float(u1.x & 0xffff0000u), acc.y);
        acc.z = fmaf(ww.y, __uint_as_float(u1.y << 16), acc.z);
        acc.w = fmaf(ww.y, __uint_as_float(u1.y & 0xffff0000u), acc.w);
        acc.x = fmaf(ww.z, __uint_as_float(u2.x << 16), acc.x);
        acc.y = fmaf(ww.z, __uint_as_float(u2.x & 0xffff0000u), acc.y);
        acc.z = fmaf(ww.z, __uint_as_float(u2.y << 16), acc.z);
        acc.w = fmaf(ww.z, __uint_as_float(u2.y & 0xffff0000u), acc.w);
        acc.x = fmaf(ww.w, __uint_as_float(u3.x << 16), acc.x);
        acc.y = fmaf(ww.w, __uint_as_float(u3.x & 0xffff0000u), acc.y);
        acc.z = fmaf(ww.w, __uint_as_float(u3.y << 16), acc.z);
        acc.w = fmaf(ww.w, __uint_as_float(u3.y & 0xffff0000u), acc.w);
    }

    if (half) s_red[q][lane] = acc;
    __syncthreads();
    if (!half) {
        float4 r = s_red[q][lane];
        acc.x += r.x; acc.y += r.y; acc.z += r.z; acc.w += r.w;
        ushort4 o;
        o.x = f2b(acc.x); o.y = f2b(acc.y); o.z = f2b(acc.z); o.w = f2b(acc.w);
        *(ushort4*)(out + (size_t)bq * 256 + ch0) = o;
    }
}

// ---------------------------------------------------------------------------
extern "C" void kernel_launch(void* const* d_in, const int* in_sizes, int n_in,
                              void* d_out, int out_size, void* d_ws, size_t ws_size,
                              hipStream_t stream) {
    const float* hidden = (const float*)d_in[0];
    const float* pos    = (const float*)d_in[1];
    const float* refp   = (const float*)d_in[2];
    const float* Wv     = (const float*)d_in[3];
    const float* bv     = (const float*)d_in[4];
    const float* Wo     = (const float*)d_in[5];
    const float* bo     = (const float*)d_in[6];
    const float* Wa     = (const float*)d_in[7];
    const float* ba     = (const float*)d_in[8];
    const float* Wout   = (const float*)d_in[9];
    const float* bout   = (const float*)d_in[10];

    float* out      = (float*)d_out;                       // (B,SEQ,256)
    float* attn_out = out + (size_t)BB * SEQ * DD;         // (B,SEQ,NH,NL,NP)

    const size_t BSD = (size_t)BB * SEQ * DD;              // 5,505,024
    char* w = (char*)d_ws;
    ushort* value_bf = (ushort*)w;  w += BSD * 2;                 // bf16 value
    float*  comb     = (float*)w;   w += (size_t)MTOT * 288 * 4;  // off|logits
    ushort* sampb    = (ushort*)w;  w += BSD * 2;                 // bf16 sampled
    ushort* hb       = (ushort*)w;  w += BSD * 2;                 // bf16 hidden
    ushort* hsb      = (ushort*)w;  w += BSD * 2;                 // bf16 hidden+pos
    ushort* Wt       = (ushort*)w;  w += (size_t)800 * 256 * 2;   // bf16 weights^T
    float*  bcomb    = (float*)w;                                 // 288 bias

    // 1. prep: hidden->bf16, hidden+pos->bf16
    {
        int n4 = (int)(BSD / 4);
        prep_acts<<<2048, 256, 0, stream>>>((const float4*)hidden, (const float4*)pos,
                                            (ushort4*)hb, (ushort4*)hsb, n4);
    }
    // 2. prep: transpose weights to bf16 [N][K] + combined bias
    prep_w<<<801, 256, 0, stream>>>(Wv, Wo, Wa, Wout, bo, ba, Wt, bcomb);

    const ushort* Wv_t    = Wt;
    const ushort* Wcomb_t = Wt + (size_t)256 * 256;   // rows: 192 Wo + 96 Wa
    const ushort* Wout_t  = Wt + (size_t)544 * 256;

    // 3. value = hidden @ Wv + bv  -> bf16
    {
        dim3 grid(DD / 64, MTOT / 128);
        gemm_mfma<true><<<grid, 256, 0, stream>>>(hb, Wv_t, bv, value_bf, MTOT, DD, DD);
    }
    // 4. comb = hs @ [Wo|Wa] + [bo|ba]  (N=288, fp32 out)
    {
        dim3 grid(5, MTOT / 128);
        gemm_mfma<false><<<grid, 256, 0, stream>>>(hsb, Wcomb_t, bcomb, comb, MTOT, 288, DD);
    }
    // 5. fused softmax + deformable sampling -> attn_out + sampled bf16
    {
        msda_sample_v6<<<MTOT / 2, 256, 0, stream>>>(value_bf, comb, refp,
                                                     attn_out, sampb);
    }
    // 6. out = sampled @ Wout + bout -> d_out
    {
        dim3 grid(DD / 64, MTOT / 128);
        gemm_mfma<false><<<grid, 256, 0, stream>>>(sampb, Wout_t, bout, out, MTOT, DD, DD);
    }
}

// Round 9
// 94.183 us; speedup vs baseline: 1.6321x; 1.0806x over previous
//
#include <hip/hip_runtime.h>
#include <hip/hip_bf16.h>
#include <math.h>

// Problem constants (Mask2Former pixel decoder / MS-deformable attention)
#define BB 4
#define SEQ 5376
#define DD 256
#define NH 8
#define NL 3
#define NP 4
#define DH 32
#define MTOT (BB * SEQ)          // 21504 rows for all GEMMs

typedef __attribute__((ext_vector_type(8))) short bf16x8;
typedef __attribute__((ext_vector_type(4))) float f32x4;

__device__ __forceinline__ ushort f2b(float f) {
    __hip_bfloat16 h = __float2bfloat16(f);
    return *reinterpret_cast<ushort*>(&h);
}

// ---------------------------------------------------------------------------
// Convert hidden -> bf16 and (hidden+pos) -> bf16 in one pass.
// ---------------------------------------------------------------------------
__global__ void prep_acts(const float4* __restrict__ h, const float4* __restrict__ p,
                          ushort4* __restrict__ hb, ushort4* __restrict__ hsb, int n4) {
    int i = blockIdx.x * blockDim.x + threadIdx.x;
    int stride = gridDim.x * blockDim.x;
    for (; i < n4; i += stride) {
        float4 a = h[i], b = p[i];
        ushort4 ua, us;
        ua.x = f2b(a.x); ua.y = f2b(a.y); ua.z = f2b(a.z); ua.w = f2b(a.w);
        us.x = f2b(a.x + b.x); us.y = f2b(a.y + b.y);
        us.z = f2b(a.z + b.z); us.w = f2b(a.w + b.w);
        hb[i] = ua;
        hsb[i] = us;
    }
}

// ---------------------------------------------------------------------------
// Transpose all 4 weight matrices (K=256 each) into Wt[800][256] bf16.
// Rows: [0,256)=Wv, [256,448)=Wo, [448,544)=Wa, [544,800)=Wout.
// Block 800: build combined bias for the merged off+logits GEMM (288 floats).
// ---------------------------------------------------------------------------
__global__ __launch_bounds__(256) void prep_w(
    const float* __restrict__ Wv, const float* __restrict__ Wo,
    const float* __restrict__ Wa, const float* __restrict__ Wout,
    const float* __restrict__ bo, const float* __restrict__ ba,
    ushort* __restrict__ Wt, float* __restrict__ bcomb) {
    int row = blockIdx.x;
    int k = threadIdx.x;
    if (row == 800) {
        for (int i = k; i < 288; i += 256)
            bcomb[i] = (i < 192) ? bo[i] : ba[i - 192];
        return;
    }
    const float* src;
    int N, n;
    if (row < 256)      { src = Wv;   N = 256; n = row; }
    else if (row < 448) { src = Wo;   N = 192; n = row - 256; }
    else if (row < 544) { src = Wa;   N = 96;  n = row - 448; }
    else                { src = Wout; N = 256; n = row - 544; }
    float v = src[(size_t)k * N + n];
    Wt[(size_t)row * 256 + k] = f2b(v);
}

// ---------------------------------------------------------------------------
// bf16 MFMA GEMM: C[M,N] = A[M,K]@W[K,N] + bias  (A bf16 [M][K], Wt bf16 [N][K])
// BM=128, BN=64, BK=64. 256 threads = 4 waves 2x2; wave tile 64x32; per
// K-step 2 sub-steps of mfma_f32_16x16x32_bf16 -> 16 MFMA per barrier pair.
// OBF: bf16 output, else fp32. N guarded.
// ---------------------------------------------------------------------------
template<bool OBF>
__global__ __launch_bounds__(256) void gemm_mfma(
    const ushort* __restrict__ A, const ushort* __restrict__ Wt,
    const float* __restrict__ bias, void* __restrict__ Cout,
    int M, int N, int K) {
    const int BM = 128, BN = 64, BK = 64, PK = 72;   // PK: padded LDS row (elems)
    __shared__ ushort As[BM][PK];
    __shared__ ushort Bs[BN][PK];
    int bm = blockIdx.y * BM;
    int bn = blockIdx.x * BN;
    int tid = threadIdx.x;
    int lane = tid & 63;
    int wid = tid >> 6;
    int wr = wid >> 1, wc = wid & 1;     // 2x2 wave grid
    int lr = lane & 15;                  // row-in-frag (A) / col (B,C)
    int kg = lane >> 4;                  // k-group 0..3

    f32x4 acc[4][2] = {};

    for (int k0 = 0; k0 < K; k0 += BK) {
        // stage A: 128 rows x 64 bf16 = 1024 chunks of 8 bf16 (16B)
        #pragma unroll
        for (int c = 0; c < 4; c++) {
            int e = tid + 256 * c;
            int row = e >> 3, q = e & 7;
            const ushort* src = A + (size_t)(bm + row) * K + k0 + 8 * q;
            *(bf16x8*)&As[row][8 * q] = *(const bf16x8*)src;
        }
        // stage B: 64 rows x 64 bf16 = 512 chunks
        #pragma unroll
        for (int c = 0; c < 2; c++) {
            int e = tid + 256 * c;
            int row = e >> 3, q = e & 7;
            int gn = bn + row;
            bf16x8 v = {0, 0, 0, 0, 0, 0, 0, 0};
            if (gn < N) v = *(const bf16x8*)(Wt + (size_t)gn * K + k0 + 8 * q);
            *(bf16x8*)&Bs[row][8 * q] = v;
        }
        __syncthreads();
        #pragma unroll
        for (int ks = 0; ks < 2; ks++) {
            bf16x8 af[4], bfr[2];
            #pragma unroll
            for (int mf = 0; mf < 4; mf++)
                af[mf] = *(bf16x8*)&As[wr * 64 + mf * 16 + lr][ks * 32 + kg * 8];
            #pragma unroll
            for (int nf = 0; nf < 2; nf++)
                bfr[nf] = *(bf16x8*)&Bs[wc * 32 + nf * 16 + lr][ks * 32 + kg * 8];
            #pragma unroll
            for (int mf = 0; mf < 4; mf++)
                #pragma unroll
                for (int nf = 0; nf < 2; nf++)
                    acc[mf][nf] = __builtin_amdgcn_mfma_f32_16x16x32_bf16(
                        af[mf], bfr[nf], acc[mf][nf], 0, 0, 0);
        }
        __syncthreads();
    }

    // epilogue: C[row][col] = acc + bias[col]
    #pragma unroll
    for (int nf = 0; nf < 2; nf++) {
        int gc = bn + wc * 32 + nf * 16 + lr;
        if (gc >= N) continue;
        float bv = bias[gc];
        #pragma unroll
        for (int mf = 0; mf < 4; mf++) {
            int gr0 = bm + wr * 64 + mf * 16 + kg * 4;
            #pragma unroll
            for (int r = 0; r < 4; r++) {
                float v = acc[mf][nf][r] + bv;
                if constexpr (OBF)
                    ((ushort*)Cout)[(size_t)(gr0 + r) * N + gc] = f2b(v);
                else
                    ((float*)Cout)[(size_t)(gr0 + r) * N + gc] = v;
            }
        }
    }
}

// ---------------------------------------------------------------------------
// Deformable sampling v7: fused softmax + tap table + 16B gathers (8 ch/lane),
// NO manual pipelining (compiler schedules). Block = 128 threads (2 waves)
// = 4 queries (32 lanes per query).
// Phase 1: 512 slots = 4q x 8h x 16 lanes (lp<12 active); 16-lane shfl
//          softmax -> attn_out; tap idx/weights -> LDS.
// Phase 2: lane5 = lane&31: h = lane5>>2, d8 = lane5&3 (8 channels, 16B).
// ---------------------------------------------------------------------------
struct Acc8 {
    float a0, a1, a2, a3, a4, a5, a6, a7;
};

__device__ __forceinline__ void fma8(Acc8& acc, float wt, uint4 u) {
    acc.a0 = fmaf(wt, __uint_as_float(u.x << 16), acc.a0);
    acc.a1 = fmaf(wt, __uint_as_float(u.x & 0xffff0000u), acc.a1);
    acc.a2 = fmaf(wt, __uint_as_float(u.y << 16), acc.a2);
    acc.a3 = fmaf(wt, __uint_as_float(u.y & 0xffff0000u), acc.a3);
    acc.a4 = fmaf(wt, __uint_as_float(u.z << 16), acc.a4);
    acc.a5 = fmaf(wt, __uint_as_float(u.z & 0xffff0000u), acc.a5);
    acc.a6 = fmaf(wt, __uint_as_float(u.w << 16), acc.a6);
    acc.a7 = fmaf(wt, __uint_as_float(u.w & 0xffff0000u), acc.a7);
}

__global__ __launch_bounds__(128) void msda_sample_v7(
    const ushort* __restrict__ value, const float* __restrict__ comb,
    const float* __restrict__ refp, float* __restrict__ attn_out,
    ushort* __restrict__ out) {
    __shared__ int4   s_idx[4][8][13];   // [q][h][lp], pad 12->13
    __shared__ float4 s_w[4][8][13];
    int tid = threadIdx.x;
    int bq0 = blockIdx.x * 4;

    // ---- phase 1: softmax + tap setup (512 slots, 4 passes of 128) ----
    #pragma unroll
    for (int it = 0; it < 4; it++) {
        int t = tid + it * 128;
        int lp = t & 15;                 // == lane&15 (128 % 16 == 0)
        int qh = t >> 4;                 // 0..31
        int q = qh >> 3, h = qh & 7;
        int bq = bq0 + q;
        bool active = lp < 12;
        const float* crow = comb + (size_t)bq * 288;
        float logit = active ? crow[192 + h * 12 + lp] : -INFINITY;
        float m = logit;
        m = fmaxf(m, __shfl_xor(m, 1, 16));
        m = fmaxf(m, __shfl_xor(m, 2, 16));
        m = fmaxf(m, __shfl_xor(m, 4, 16));
        m = fmaxf(m, __shfl_xor(m, 8, 16));
        float e = active ? expf(logit - m) : 0.f;
        float s = e;
        s += __shfl_xor(s, 1, 16);
        s += __shfl_xor(s, 2, 16);
        s += __shfl_xor(s, 4, 16);
        s += __shfl_xor(s, 8, 16);
        float aw = e / s;
        if (active) {
            attn_out[(size_t)bq * 96 + h * 12 + lp] = aw;
            int l = lp >> 2;
            int b = bq / SEQ;
            int Wl = 64 >> l;
            float fW = (float)Wl;
            float rx = refp[(size_t)bq * 6 + 2 * l];
            float ry = refp[(size_t)bq * 6 + 2 * l + 1];
            float ox = crow[h * 24 + lp * 2];
            float oy = crow[h * 24 + lp * 2 + 1];
            float x = rx * fW + ox - 0.5f;
            float y = ry * fW + oy - 0.5f;
            float x0f = floorf(x), y0f = floorf(y);
            float wx = x - x0f, wy = y - y0f;
            int x0 = (int)x0f, y0 = (int)y0f;
            int x1 = x0 + 1, y1 = y0 + 1;
            float vx0 = (x0 >= 0 && x0 < Wl) ? 1.f : 0.f;
            float vx1 = (x1 >= 0 && x1 < Wl) ? 1.f : 0.f;
            float vy0 = (y0 >= 0 && y0 < Wl) ? 1.f : 0.f;   // square levels
            float vy1 = (y1 >= 0 && y1 < Wl) ? 1.f : 0.f;
            int xc0 = min(max(x0, 0), Wl - 1);
            int xc1 = min(max(x1, 0), Wl - 1);
            int yc0 = min(max(y0, 0), Wl - 1);
            int yc1 = min(max(y1, 0), Wl - 1);
            int st = (l == 0) ? 0 : ((l == 1) ? 4096 : 5120);
            int rowbase = b * SEQ + st;
            s_idx[q][h][lp] = make_int4((rowbase + yc0 * Wl + xc0) << 8,
                                        (rowbase + yc0 * Wl + xc1) << 8,
                                        (rowbase + yc1 * Wl + xc0) << 8,
                                        (rowbase + yc1 * Wl + xc1) << 8);
            s_w[q][h][lp] = make_float4(aw * (1.f - wx) * (1.f - wy) * vx0 * vy0,
                                        aw * wx * (1.f - wy) * vx1 * vy0,
                                        aw * (1.f - wx) * wy * vx0 * vy1,
                                        aw * wx * wy * vx1 * vy1);
        }
    }
    __syncthreads();

    // ---- phase 2: gather + FMA; 8 channels (16B) per lane ----
    int wave = tid >> 6, lane = tid & 63;
    int q2 = lane >> 5;
    int lane5 = lane & 31;
    int h = lane5 >> 2, d8 = lane5 & 3;
    int q = wave * 2 + q2;
    int bq = bq0 + q;
    int ch0 = h * 32 + d8 * 8;
    const ushort* vb = value + ch0;

    Acc8 acc = {0.f, 0.f, 0.f, 0.f, 0.f, 0.f, 0.f, 0.f};
    #pragma unroll
    for (int lp = 0; lp < 12; lp++) {
        int4 ii = s_idx[q][h][lp];
        float4 ww = s_w[q][h][lp];
        uint4 u0 = *(const uint4*)(vb + ii.x);
        uint4 u1 = *(const uint4*)(vb + ii.y);
        uint4 u2 = *(const uint4*)(vb + ii.z);
        uint4 u3 = *(const uint4*)(vb + ii.w);
        fma8(acc, ww.x, u0);
        fma8(acc, ww.y, u1);
        fma8(acc, ww.z, u2);
        fma8(acc, ww.w, u3);
    }

    bf16x8 o;
    o[0] = (short)f2b(acc.a0); o[1] = (short)f2b(acc.a1);
    o[2] = (short)f2b(acc.a2); o[3] = (short)f2b(acc.a3);
    o[4] = (short)f2b(acc.a4); o[5] = (short)f2b(acc.a5);
    o[6] = (short)f2b(acc.a6); o[7] = (short)f2b(acc.a7);
    *(bf16x8*)(out + (size_t)bq * 256 + ch0) = o;
}

// ---------------------------------------------------------------------------
extern "C" void kernel_launch(void* const* d_in, const int* in_sizes, int n_in,
                              void* d_out, int out_size, void* d_ws, size_t ws_size,
                              hipStream_t stream) {
    const float* hidden = (const float*)d_in[0];
    const float* pos    = (const float*)d_in[1];
    const float* refp   = (const float*)d_in[2];
    const float* Wv     = (const float*)d_in[3];
    const float* bv     = (const float*)d_in[4];
    const float* Wo     = (const float*)d_in[5];
    const float* bo     = (const float*)d_in[6];
    const float* Wa     = (const float*)d_in[7];
    const float* ba     = (const float*)d_in[8];
    const float* Wout   = (const float*)d_in[9];
    const float* bout   = (const float*)d_in[10];

    float* out      = (float*)d_out;                       // (B,SEQ,256)
    float* attn_out = out + (size_t)BB * SEQ * DD;         // (B,SEQ,NH,NL,NP)

    const size_t BSD = (size_t)BB * SEQ * DD;              // 5,505,024
    char* w = (char*)d_ws;
    ushort* value_bf = (ushort*)w;  w += BSD * 2;                 // bf16 value
    float*  comb     = (float*)w;   w += (size_t)MTOT * 288 * 4;  // off|logits
    ushort* sampb    = (ushort*)w;  w += BSD * 2;                 // bf16 sampled
    ushort* hb       = (ushort*)w;  w += BSD * 2;                 // bf16 hidden
    ushort* hsb      = (ushort*)w;  w += BSD * 2;                 // bf16 hidden+pos
    ushort* Wt       = (ushort*)w;  w += (size_t)800 * 256 * 2;   // bf16 weights^T
    float*  bcomb    = (float*)w;                                 // 288 bias

    // 1. prep: hidden->bf16, hidden+pos->bf16
    {
        int n4 = (int)(BSD / 4);
        prep_acts<<<2048, 256, 0, stream>>>((const float4*)hidden, (const float4*)pos,
                                            (ushort4*)hb, (ushort4*)hsb, n4);
    }
    // 2. prep: transpose weights to bf16 [N][K] + combined bias
    prep_w<<<801, 256, 0, stream>>>(Wv, Wo, Wa, Wout, bo, ba, Wt, bcomb);

    const ushort* Wv_t    = Wt;
    const ushort* Wcomb_t = Wt + (size_t)256 * 256;   // rows: 192 Wo + 96 Wa
    const ushort* Wout_t  = Wt + (size_t)544 * 256;

    // 3. value = hidden @ Wv + bv  -> bf16
    {
        dim3 grid(DD / 64, MTOT / 128);
        gemm_mfma<true><<<grid, 256, 0, stream>>>(hb, Wv_t, bv, value_bf, MTOT, DD, DD);
    }
    // 4. comb = hs @ [Wo|Wa] + [bo|ba]  (N=288, fp32 out)
    {
        dim3 grid(5, MTOT / 128);
        gemm_mfma<false><<<grid, 256, 0, stream>>>(hsb, Wcomb_t, bcomb, comb, MTOT, 288, DD);
    }
    // 5. fused softmax + deformable sampling -> attn_out + sampled bf16
    {
        msda_sample_v7<<<MTOT / 4, 128, 0, stream>>>(value_bf, comb, refp,
                                                     attn_out, sampb);
    }
    // 6. out = sampled @ Wout + bout -> d_out
    {
        dim3 grid(DD / 64, MTOT / 128);
        gemm_mfma<false><<<grid, 256, 0, stream>>>(sampb, Wout_t, bout, out, MTOT, DD, DD);
    }
}